// Round 13
// baseline (4172.259 us; speedup 1.0000x reference)
//
#include <hip/hip_runtime.h>
#include <hip/hip_bf16.h>

typedef __attribute__((ext_vector_type(8))) short bf8;    // 8 bf16 (4 VGPRs)
typedef __attribute__((ext_vector_type(4))) float f32x4;  // MFMA accumulator
typedef __attribute__((ext_vector_type(2))) unsigned int u32x2;  // asm-safe 64-bit payload

#define T_SEQ 1024

__device__ __forceinline__ float sigm(float x) { return 1.f / (1.f + __expf(-x)); }
__device__ __forceinline__ float tanh_(float x) { return 2.f / (1.f + __expf(-2.f * x)) - 1.f; }

__device__ __forceinline__ short bf16s(float x) {
    union { __hip_bfloat16 h; short s; } u;
    u.h = __float2bfloat16(x);
    return u.s;
}

__device__ __forceinline__ bf8 pack_bf8(const float4 a, const float4 b) {
    bf8 r;
    r[0] = bf16s(a.x); r[1] = bf16s(a.y); r[2] = bf16s(a.z); r[3] = bf16s(a.w);
    r[4] = bf16s(b.x); r[5] = bf16s(b.y); r[6] = bf16s(b.z); r[7] = bf16s(b.w);
    return r;
}

// ---- sc1 (device-scope, LLC-coherent) access helpers -----------------------
// sc1 = device scope: loads bypass L1 and the non-device-coherent per-XCD L2,
// reading the coherence point; stores write through to it. Proven cross-XCD
// correct on this problem (rounds 3-12). h-exchange = r3 protocol (measured
// best of nine variants); xproj fused + overlapped (r11, -240 us); rec at
// setprio(1) (r12). ROUND-13 change: the h-flag poll is software-pipelined —
// TWO outstanding probes, wait-older via vmcnt(1) (counted-waitcnt idiom) —
// halving the flag sampling period from ~1 LLC RT to ~RT/2, cutting expected
// detection latency by ~RT/4 per step. Guarded (4096 iters) -> fail-fast.
__device__ __forceinline__ void store_sc1_b64(void* p, unsigned int lo, unsigned int hi) {
    u32x2 v; v[0] = lo; v[1] = hi;
    asm volatile("global_store_dwordx2 %0, %1, off sc1" :: "v"(p), "v"(v) : "memory");
}
__device__ __forceinline__ void store_sc1_b32(void* p, unsigned int v) {
    asm volatile("global_store_dword %0, %1, off sc1" :: "v"(p), "v"(v) : "memory");
}
__device__ __forceinline__ void store_sc1_b16(void* p, unsigned short v) {
    unsigned int vv = v;
    asm volatile("global_store_short %0, %1, off sc1" :: "v"(p), "v"(vv) : "memory");
}
__device__ __forceinline__ unsigned int load_sc1_b32(const void* p) {
    unsigned int v;
    asm volatile("global_load_dword %0, %1, off sc1\n"
                 "s_waitcnt vmcnt(0)"
                 : "=v"(v) : "v"(p) : "memory");
    return v;
}
__device__ __forceinline__ bf8 load_sc1_b128(const void* p) {
    bf8 v;  // issued without waitcnt so the 8 frag loads pipeline
    asm volatile("global_load_dwordx4 %0, %1, off sc1" : "=v"(v) : "v"(p) : "memory");
    return v;
}

// Double-probe pipelined poll: spin until flag >= tau for ALL active lanes.
// Two probes in flight; each s_waitcnt vmcnt(1) waits only for the OLDER one,
// so the flag is sampled at the LLC every ~RT/2 instead of every ~RT.
// v_cmp writes 0 for inactive lanes -> s_cbranch_vccz == "all active ready".
// Guard (4096 double-iterations) bounds the spin: on pathology we proceed and
// the tag-free r3 drain-then-flag invariant means a guard exit only happens if
// the producer truly stalled -> verification fails fast, never a hang.
__device__ __forceinline__ void poll_flag_ge(const int* p, int tau) {
    int a, b, g;
    asm volatile(
        "global_load_dword %[a], %[p], off sc1\n\t"
        "global_load_dword %[b], %[p], off sc1\n\t"
        "s_mov_b32 %[g], 0\n\t"
        "Lpoll%=:\n\t"
        "s_waitcnt vmcnt(1)\n\t"                    // older probe (a) complete
        "v_cmp_gt_i32 vcc, %[t], %[a]\n\t"          // lanes with tau > a: not ready
        "s_cbranch_vccz Ldone%=\n\t"
        "global_load_dword %[a], %[p], off sc1\n\t"
        "s_add_u32 %[g], %[g], 1\n\t"
        "s_cmp_ge_u32 %[g], 0x1000\n\t"
        "s_cbranch_scc1 Ldone%=\n\t"
        "s_waitcnt vmcnt(1)\n\t"                    // older probe (b) complete
        "v_cmp_gt_i32 vcc, %[t], %[b]\n\t"
        "s_cbranch_vccz Ldone%=\n\t"
        "global_load_dword %[b], %[p], off sc1\n\t"
        "s_branch Lpoll%=\n\t"
        "Ldone%=:\n\t"
        "s_waitcnt vmcnt(0)\n\t"                    // drain leftover probe
        : [a]"=&v"(a), [b]"=&v"(b), [g]"=&s"(g)
        : [p]"v"(p), [t]"v"(tau)
        : "vcc", "scc", "memory");
}

// ---------------- Phase 0: zero exchange/flag/counter state (graph-safe) ----------------
__global__ __launch_bounds__(256) void init_kernel(unsigned int* __restrict__ p, int n)
{
    const int i = blockIdx.x * 256 + threadIdx.x;
    if (i < n) p[i] = 0u;
}

// ---------------- Fused kernel: rec (blocks 0..31) + xproj (blocks 32..8223) ----------------
// xproj block order is stage-major: stage s in [0,8) covers (fwd chunk s) and
// (bwd chunk 7-s) for all 64 batches x 8 n-tiles — both directions' consumption
// order. Deadlock-free in ANY dispatch order: xproj never waits; rec waits only
// on monotonic counters that xproj unconditionally reaches; worst case degrades
// to the serial anchor (~4.4 ms).
__global__ __launch_bounds__(256, 1) void fused_kernel(
    const float* __restrict__ X,
    const float* __restrict__ WihF,
    const float* __restrict__ bihF,
    const float* __restrict__ bhhF,
    const float* __restrict__ WihB,
    const float* __restrict__ bihB,
    const float* __restrict__ bhhB,
    const float* __restrict__ WhhF,
    const float* __restrict__ WhhB,
    __hip_bfloat16* __restrict__ XpF,
    __hip_bfloat16* __restrict__ XpB,
    __hip_bfloat16* __restrict__ hexch,
    int* __restrict__ flags,
    int* __restrict__ cnt,        // [dir=2][chunk=8] completion counters (target 512)
    float* __restrict__ out)
{
    __shared__ __align__(16) unsigned char smem[16384];   // xproj: As|Bs; rec: hstage
    const int tid  = threadIdx.x;
    const int lane = tid & 63;
    const int quad = lane >> 4;
    const int l16  = lane & 15;

    if (blockIdx.x < 32) {
        // ================= REC body (r12 + pipelined flag poll) =================
        __builtin_amdgcn_s_setprio(1);   // win issue arbitration vs co-resident xproj waves

        const int wg  = blockIdx.x;
        const int dir = wg >> 4;
        const int s   = wg & 15;
        const int w   = tid >> 6;       // wave = batch tile (16 batches)

        const __hip_bfloat16* Xp = dir ? XpB : XpF;
        const float* Whh         = dir ? WhhB : WhhF;
        unsigned int* hexchU     = (unsigned int*)hexch;
        unsigned int* hstage     = (unsigned int*)smem;   // [64 b][16 j] bf16 = 2 KB

        // Preload Whh slice: Bf[gate][kstep], B-frag layout n=l16, k=quad*8+j.
        bf8 Bf[4][8];
#pragma unroll
        for (int g = 0; g < 4; g++)
#pragma unroll
            for (int k = 0; k < 8; k++) {
                const float* p = Whh + (size_t)(g * 256 + s * 16 + l16) * 256 + k * 32 + quad * 8;
                Bf[g][k] = pack_bf8(*(const float4*)p, *(const float4*)(p + 4));
            }

        float c[4] = {0.f, 0.f, 0.f, 0.f};   // cell state, fp32, never rounded

        for (int tau = 0; tau < T_SEQ; tau++) {
            const int t = dir ? (T_SEQ - 1 - tau) : tau;

            // Gate on Xp chunk readiness (once per 128 steps; counter at LLC).
            if ((tau & 127) == 0) {
                if (tid == 0) {
                    const int chunk = dir ? (7 - (tau >> 7)) : (tau >> 7);
                    const int* cp = &cnt[dir * 8 + chunk];
                    int guard = 0;
                    while ((int)load_sc1_b32(cp) < 512 && ++guard < (1 << 20)) { }
                }
                __syncthreads();
            }

            // Spin: 16 lanes of wave 0, one h-flag each (128 B apart),
            // double-probe pipelined sc1 poll (samples flag every ~RT/2).
            if (tid < 16) {
                poll_flag_ge(&flags[(dir * 16 + tid) * 32], tau);
            }
            __syncthreads();

            // Xp loads (raw bf16 bits; accumulated after the MFMAs). Fresh from LLC:
            // producer wrote them sc1 write-through; NT loads don't hit stale L1/L2.
            unsigned short xpu[4][4];
#pragma unroll
            for (int g = 0; g < 4; g++)
#pragma unroll
                for (int r = 0; r < 4; r++) {
                    const int b = w * 16 + quad * 4 + r;
                    xpu[g][r] = __builtin_nontemporal_load(
                        (const unsigned short*)&Xp[((size_t)t * 64 + b) * 1024 + g * 256 + s * 16 + l16]);
                }

            // A-frags (h_tau) from hexch buf tau&1: sc1 loads read the LLC directly.
            const __hip_bfloat16* hb = hexch + ((size_t)((tau & 1) * 2 + dir) * 16) * 1024;
            bf8 Af[8];
#pragma unroll
            for (int k = 0; k < 8; k++) {
                const int sA = k * 2 + (quad >> 1);          // slice holding k-cols [k*32+quad*8, +8)
                Af[k] = load_sc1_b128(hb + (size_t)sA * 1024 + (w * 16 + l16) * 16 + (quad & 1) * 8);
            }
            asm volatile("s_waitcnt vmcnt(0)" ::: "memory");
            __builtin_amdgcn_sched_barrier(0);   // rule 18: keep MFMAs below the asm waitcnt

            f32x4 acc[4];
            const f32x4 zero = {0.f, 0.f, 0.f, 0.f};
#pragma unroll
            for (int g = 0; g < 4; g++) acc[g] = zero;
#pragma unroll
            for (int k = 0; k < 8; k++)
#pragma unroll
                for (int g = 0; g < 4; g++)
                    acc[g] = __builtin_amdgcn_mfma_f32_16x16x32_bf16(Af[k], Bf[g][k], acc[g], 0, 0, 0);

            // Gates; lane holds i,f,g,o for (b = w*16+quad*4+r, j = s*16+l16).
            float hv[4];
#pragma unroll
            for (int r = 0; r < 4; r++) {
                union { unsigned int u; float f; } cv0, cv1, cv2, cv3;
                cv0.u = (unsigned int)xpu[0][r] << 16;
                cv1.u = (unsigned int)xpu[1][r] << 16;
                cv2.u = (unsigned int)xpu[2][r] << 16;
                cv3.u = (unsigned int)xpu[3][r] << 16;
                const float ig = sigm(acc[0][r] + cv0.f);
                const float fg = sigm(acc[1][r] + cv1.f);
                const float gg = tanh_(acc[2][r] + cv2.f);
                const float og = sigm(acc[3][r] + cv3.f);
                c[r] = fg * c[r] + ig * gg;
                hv[r] = og * tanh_(c[r]);
                const int b = w * 16 + quad * 4 + r;
                ((__hip_bfloat16*)hstage)[b * 16 + l16] = __float2bfloat16(hv[r]);
            }
            __syncthreads();   // hstage complete

            // Publish h_{tau+1}: sc1 write-through dwordx2 per thread into the LLC.
            {
                unsigned int* dst = hexchU + ((size_t)(((tau + 1) & 1) * 2 + dir) * 16 + s) * 512;
                store_sc1_b64(&dst[2 * tid], hstage[2 * tid], hstage[2 * tid + 1]);
            }
            asm volatile("s_waitcnt vmcnt(0)" ::: "memory");   // per-wave drain: data in LLC
            __syncthreads();                                    // all waves drained
            if (tid == 0)
                store_sc1_b32(&flags[(dir * 16 + s) * 32], (unsigned int)(tau + 1));

            // Output stores off the critical path (drain overlaps next spin).
#pragma unroll
            for (int r = 0; r < 4; r++) {
                const int b = w * 16 + quad * 4 + r;
                __builtin_nontemporal_store(hv[r], &out[((size_t)b * T_SEQ + t) * 512 + dir * 256 + s * 16 + l16]);
            }
        }
    } else {
        // ================= XPROJ body (stage-remapped, sc1 stores, counter signal) =================
        const int xp4 = blockIdx.x - 32;          // [0, 8192)
        const int st  = xp4 >> 10;                // stage 0..7
        const int r1  = xp4 & 1023;
        const int dir = r1 >> 9;
        const int r2  = r1 & 511;
        const int yb  = r2 >> 6;                  // n-tile 0..7
        const int bb  = r2 & 63;                  // batch 0..63
        const int chunk = dir ? (7 - st) : st;    // t-chunk this block produces
        const int m0 = bb * 1024 + chunk * 128;   // 128 contiguous m within batch bb
        const int n0 = yb * 128;

        const float* W  = dir ? WihB : WihF;
        const float* bi = dir ? bihB : bihF;
        const float* bh = dir ? bhhB : bhhF;
        __hip_bfloat16* Xp = dir ? XpB : XpF;

        short* As = (short*)smem;                 // 128 x 32
        short* Bs = (short*)(smem + 8192);        // 128 x 32

        const int w2   = tid >> 6;
        const int wr   = w2 >> 1, wc = w2 & 1;    // 2x2 wave grid, 64x64 per wave
        const int srow = tid >> 2;                // staging row within 64-row half
        const int scg  = tid & 3;                 // 8-col group

        f32x4 acc[4][4] = {};

        for (int kk = 0; kk < 512; kk += 32) {
            const float* pa0 = X + (size_t)(m0 + srow)      * 512 + kk + scg * 8;
            const float* pa1 = X + (size_t)(m0 + 64 + srow) * 512 + kk + scg * 8;
            const float* pb0 = W + (size_t)(n0 + srow)      * 512 + kk + scg * 8;
            const float* pb1 = W + (size_t)(n0 + 64 + srow) * 512 + kk + scg * 8;
            bf8 a0 = pack_bf8(*(const float4*)pa0, *(const float4*)(pa0 + 4));
            bf8 a1 = pack_bf8(*(const float4*)pa1, *(const float4*)(pa1 + 4));
            bf8 b0 = pack_bf8(*(const float4*)pb0, *(const float4*)(pb0 + 4));
            bf8 b1 = pack_bf8(*(const float4*)pb1, *(const float4*)(pb1 + 4));
            __syncthreads();  // previous iteration's LDS reads done
            *(bf8*)&As[(srow)      * 32 + scg * 8] = a0;
            *(bf8*)&As[(64 + srow) * 32 + scg * 8] = a1;
            *(bf8*)&Bs[(srow)      * 32 + scg * 8] = b0;
            *(bf8*)&Bs[(64 + srow) * 32 + scg * 8] = b1;
            __syncthreads();

            bf8 af[4], bfr[4];
#pragma unroll
            for (int mt = 0; mt < 4; mt++)
                af[mt] = *(const bf8*)&As[(wr * 64 + mt * 16 + l16) * 32 + quad * 8];
#pragma unroll
            for (int nt = 0; nt < 4; nt++)
                bfr[nt] = *(const bf8*)&Bs[(wc * 64 + nt * 16 + l16) * 32 + quad * 8];
#pragma unroll
            for (int mt = 0; mt < 4; mt++)
#pragma unroll
                for (int nt = 0; nt < 4; nt++)
                    acc[mt][nt] = __builtin_amdgcn_mfma_f32_16x16x32_bf16(af[mt], bfr[nt], acc[mt][nt], 0, 0, 0);
        }

        // Epilogue: sc1 write-through stores (visible at LLC), then drain + signal.
#pragma unroll
        for (int nt = 0; nt < 4; nt++) {
            const int n = n0 + wc * 64 + nt * 16 + l16;
            const float bias = bi[n] + bh[n];
#pragma unroll
            for (int mt = 0; mt < 4; mt++) {
#pragma unroll
                for (int r = 0; r < 4; r++) {
                    const int m = m0 + wr * 64 + mt * 16 + quad * 4 + r;   // C/D: row=quad*4+r, col=l16
                    const int b = m >> 10, t = m & 1023;                    // m = b*1024 + t
                    store_sc1_b16(&Xp[((size_t)t * 64 + b) * 1024 + n],
                                  (unsigned short)bf16s(acc[mt][nt][r] + bias));
                }
            }
        }
        asm volatile("s_waitcnt vmcnt(0)" ::: "memory");   // per-wave drain: Xp in LLC
        __syncthreads();                                    // all waves drained
        if (tid == 0) atomicAdd(&cnt[dir * 8 + chunk], 1);  // device-scope, lands at LLC
    }
}

extern "C" void kernel_launch(void* const* d_in, const int* in_sizes, int n_in,
                              void* d_out, int out_size, void* d_ws, size_t ws_size,
                              hipStream_t stream)
{
    const float* X    = (const float*)d_in[0];
    const float* WihF = (const float*)d_in[1];
    const float* WhhF = (const float*)d_in[2];
    const float* bihF = (const float*)d_in[3];
    const float* bhhF = (const float*)d_in[4];
    const float* WihB = (const float*)d_in[5];
    const float* WhhB = (const float*)d_in[6];
    const float* bihB = (const float*)d_in[7];
    const float* bhhB = (const float*)d_in[8];
    float* out = (float*)d_out;

    char* ws = (char*)d_ws;
    __hip_bfloat16* XpF   = (__hip_bfloat16*)ws;                           // 128 MB
    __hip_bfloat16* XpB   = (__hip_bfloat16*)(ws + 134217728);             // 128 MB
    __hip_bfloat16* hexch = (__hip_bfloat16*)(ws + 268435456);             // 128 KB
    int*            flags = (int*)(ws + 268435456 + 131072);               // 4 KB (128 B spacing)
    int*            cnt   = (int*)(ws + 268435456 + 131072 + 4096);        // 64 B

    // Zero h_0 buffers, flags (0 == "h_0 ready") and chunk counters each replay.
    const int initN = (131072 + 4096 + 64) / 4;
    init_kernel<<<(initN + 255) / 256, 256, 0, stream>>>((unsigned int*)(ws + 268435456), initN);

    // One fused dispatch: 32 rec WGs (dispatched first) + 8192 stage-ordered xproj WGs.
    fused_kernel<<<8224, 256, 0, stream>>>(X, WihF, bihF, bhhF, WihB, bihB, bhhB,
                                           WhhF, WhhB, XpF, XpB, hexch, flags, cnt, out);
}

// Round 14
// 4135.780 us; speedup vs baseline: 1.0088x; 1.0088x over previous
//
#include <hip/hip_runtime.h>
#include <hip/hip_bf16.h>

typedef __attribute__((ext_vector_type(8))) short bf8;    // 8 bf16 (4 VGPRs)
typedef __attribute__((ext_vector_type(4))) float f32x4;  // MFMA accumulator
typedef __attribute__((ext_vector_type(2))) unsigned int u32x2;  // asm-safe 64-bit payload

#define T_SEQ 1024

__device__ __forceinline__ float sigm(float x) { return 1.f / (1.f + __expf(-x)); }
__device__ __forceinline__ float tanh_(float x) { return 2.f / (1.f + __expf(-2.f * x)) - 1.f; }

__device__ __forceinline__ short bf16s(float x) {
    union { __hip_bfloat16 h; short s; } u;
    u.h = __float2bfloat16(x);
    return u.s;
}

__device__ __forceinline__ bf8 pack_bf8(const float4 a, const float4 b) {
    bf8 r;
    r[0] = bf16s(a.x); r[1] = bf16s(a.y); r[2] = bf16s(a.z); r[3] = bf16s(a.w);
    r[4] = bf16s(b.x); r[5] = bf16s(b.y); r[6] = bf16s(b.z); r[7] = bf16s(b.w);
    return r;
}

// ---- sc1 (device-scope, LLC-coherent) access helpers -----------------------
// FINAL STATE (session summary in counters/commits):
//   - h-exchange: r3 drain-then-flag protocol. Measured best of TEN variants
//     (r3-r9, r13); every hop-removal or merge attempt regressed or was null.
//   - xproj fused into the rec dispatch with stage-ordered chunk gating (r11,
//     total 4400 -> 4160 us; xproj's ~450 us fully hidden under the rec chain).
//   - rec blocks at setprio(1) (r12, fused 4069 -> 4024 us).
//   - r13's pipelined double-probe poll: NULL (same-address probes don't halve
//     sampling period) — reverted to the simple poll.
// Structural floor: 1024 serial steps x (~2 LLC RT + detect + compute) ~ 9.5k
// cy/step = ~4.0 ms fused. Counters (HBM 4.8%, Mfma 2%, VALU 5.6%) confirm a
// serial-latency bound, not BW/compute. Escapes closed: batch-decomposition is
// compute-bound (~10k cy/step/CU); XCD-local L2 exchange failed correctness (r2).
__device__ __forceinline__ void store_sc1_b64(void* p, unsigned int lo, unsigned int hi) {
    u32x2 v; v[0] = lo; v[1] = hi;
    asm volatile("global_store_dwordx2 %0, %1, off sc1" :: "v"(p), "v"(v) : "memory");
}
__device__ __forceinline__ void store_sc1_b32(void* p, unsigned int v) {
    asm volatile("global_store_dword %0, %1, off sc1" :: "v"(p), "v"(v) : "memory");
}
__device__ __forceinline__ void store_sc1_b16(void* p, unsigned short v) {
    unsigned int vv = v;
    asm volatile("global_store_short %0, %1, off sc1" :: "v"(p), "v"(vv) : "memory");
}
__device__ __forceinline__ unsigned int load_sc1_b32(const void* p) {
    unsigned int v;
    asm volatile("global_load_dword %0, %1, off sc1\n"
                 "s_waitcnt vmcnt(0)"
                 : "=v"(v) : "v"(p) : "memory");
    return v;
}
__device__ __forceinline__ bf8 load_sc1_b128(const void* p) {
    bf8 v;  // issued without waitcnt so the 8 frag loads pipeline
    asm volatile("global_load_dwordx4 %0, %1, off sc1" : "=v"(v) : "v"(p) : "memory");
    return v;
}

// ---------------- Phase 0: zero exchange/flag/counter state (graph-safe) ----------------
__global__ __launch_bounds__(256) void init_kernel(unsigned int* __restrict__ p, int n)
{
    const int i = blockIdx.x * 256 + threadIdx.x;
    if (i < n) p[i] = 0u;
}

// ---------------- Fused kernel: rec (blocks 0..31) + xproj (blocks 32..8223) ----------------
// xproj block order is stage-major: stage s in [0,8) covers (fwd chunk s) and
// (bwd chunk 7-s) for all 64 batches x 8 n-tiles — both directions' consumption
// order. Deadlock-free in ANY dispatch order: xproj never waits; rec waits only
// on monotonic counters that xproj unconditionally reaches; worst case degrades
// to the serial anchor (~4.4 ms).
__global__ __launch_bounds__(256, 1) void fused_kernel(
    const float* __restrict__ X,
    const float* __restrict__ WihF,
    const float* __restrict__ bihF,
    const float* __restrict__ bhhF,
    const float* __restrict__ WihB,
    const float* __restrict__ bihB,
    const float* __restrict__ bhhB,
    const float* __restrict__ WhhF,
    const float* __restrict__ WhhB,
    __hip_bfloat16* __restrict__ XpF,
    __hip_bfloat16* __restrict__ XpB,
    __hip_bfloat16* __restrict__ hexch,
    int* __restrict__ flags,
    int* __restrict__ cnt,        // [dir=2][chunk=8] completion counters (target 512)
    float* __restrict__ out)
{
    __shared__ __align__(16) unsigned char smem[16384];   // xproj: As|Bs; rec: hstage
    const int tid  = threadIdx.x;
    const int lane = tid & 63;
    const int quad = lane >> 4;
    const int l16  = lane & 15;

    if (blockIdx.x < 32) {
        // ================= REC body (r3 protocol + setprio(1)) =================
        __builtin_amdgcn_s_setprio(1);   // win issue arbitration vs co-resident xproj waves

        const int wg  = blockIdx.x;
        const int dir = wg >> 4;
        const int s   = wg & 15;
        const int w   = tid >> 6;       // wave = batch tile (16 batches)

        const __hip_bfloat16* Xp = dir ? XpB : XpF;
        const float* Whh         = dir ? WhhB : WhhF;
        unsigned int* hexchU     = (unsigned int*)hexch;
        unsigned int* hstage     = (unsigned int*)smem;   // [64 b][16 j] bf16 = 2 KB

        // Preload Whh slice: Bf[gate][kstep], B-frag layout n=l16, k=quad*8+j.
        bf8 Bf[4][8];
#pragma unroll
        for (int g = 0; g < 4; g++)
#pragma unroll
            for (int k = 0; k < 8; k++) {
                const float* p = Whh + (size_t)(g * 256 + s * 16 + l16) * 256 + k * 32 + quad * 8;
                Bf[g][k] = pack_bf8(*(const float4*)p, *(const float4*)(p + 4));
            }

        float c[4] = {0.f, 0.f, 0.f, 0.f};   // cell state, fp32, never rounded

        for (int tau = 0; tau < T_SEQ; tau++) {
            const int t = dir ? (T_SEQ - 1 - tau) : tau;

            // Gate on Xp chunk readiness (once per 128 steps; counter at LLC).
            if ((tau & 127) == 0) {
                if (tid == 0) {
                    const int chunk = dir ? (7 - (tau >> 7)) : (tau >> 7);
                    const int* cp = &cnt[dir * 8 + chunk];
                    int guard = 0;
                    while ((int)load_sc1_b32(cp) < 512 && ++guard < (1 << 20)) { }
                }
                __syncthreads();
            }

            // Spin: 16 lanes of wave 0, one h-flag each (128 B apart), sc1 hard poll.
            if (tid < 16) {
                int* f = &flags[(dir * 16 + tid) * 32];
                while ((int)load_sc1_b32(f) < tau) { }
            }
            __syncthreads();

            // Xp loads (raw bf16 bits; accumulated after the MFMAs). Fresh from LLC:
            // producer wrote them sc1 write-through; NT loads don't hit stale L1/L2.
            unsigned short xpu[4][4];
#pragma unroll
            for (int g = 0; g < 4; g++)
#pragma unroll
                for (int r = 0; r < 4; r++) {
                    const int b = w * 16 + quad * 4 + r;
                    xpu[g][r] = __builtin_nontemporal_load(
                        (const unsigned short*)&Xp[((size_t)t * 64 + b) * 1024 + g * 256 + s * 16 + l16]);
                }

            // A-frags (h_tau) from hexch buf tau&1: sc1 loads read the LLC directly.
            const __hip_bfloat16* hb = hexch + ((size_t)((tau & 1) * 2 + dir) * 16) * 1024;
            bf8 Af[8];
#pragma unroll
            for (int k = 0; k < 8; k++) {
                const int sA = k * 2 + (quad >> 1);          // slice holding k-cols [k*32+quad*8, +8)
                Af[k] = load_sc1_b128(hb + (size_t)sA * 1024 + (w * 16 + l16) * 16 + (quad & 1) * 8);
            }
            asm volatile("s_waitcnt vmcnt(0)" ::: "memory");
            __builtin_amdgcn_sched_barrier(0);   // rule 18: keep MFMAs below the asm waitcnt

            f32x4 acc[4];
            const f32x4 zero = {0.f, 0.f, 0.f, 0.f};
#pragma unroll
            for (int g = 0; g < 4; g++) acc[g] = zero;
#pragma unroll
            for (int k = 0; k < 8; k++)
#pragma unroll
                for (int g = 0; g < 4; g++)
                    acc[g] = __builtin_amdgcn_mfma_f32_16x16x32_bf16(Af[k], Bf[g][k], acc[g], 0, 0, 0);

            // Gates; lane holds i,f,g,o for (b = w*16+quad*4+r, j = s*16+l16).
            float hv[4];
#pragma unroll
            for (int r = 0; r < 4; r++) {
                union { unsigned int u; float f; } cv0, cv1, cv2, cv3;
                cv0.u = (unsigned int)xpu[0][r] << 16;
                cv1.u = (unsigned int)xpu[1][r] << 16;
                cv2.u = (unsigned int)xpu[2][r] << 16;
                cv3.u = (unsigned int)xpu[3][r] << 16;
                const float ig = sigm(acc[0][r] + cv0.f);
                const float fg = sigm(acc[1][r] + cv1.f);
                const float gg = tanh_(acc[2][r] + cv2.f);
                const float og = sigm(acc[3][r] + cv3.f);
                c[r] = fg * c[r] + ig * gg;
                hv[r] = og * tanh_(c[r]);
                const int b = w * 16 + quad * 4 + r;
                ((__hip_bfloat16*)hstage)[b * 16 + l16] = __float2bfloat16(hv[r]);
            }
            __syncthreads();   // hstage complete

            // Publish h_{tau+1}: sc1 write-through dwordx2 per thread into the LLC.
            {
                unsigned int* dst = hexchU + ((size_t)(((tau + 1) & 1) * 2 + dir) * 16 + s) * 512;
                store_sc1_b64(&dst[2 * tid], hstage[2 * tid], hstage[2 * tid + 1]);
            }
            asm volatile("s_waitcnt vmcnt(0)" ::: "memory");   // per-wave drain: data in LLC
            __syncthreads();                                    // all waves drained
            if (tid == 0)
                store_sc1_b32(&flags[(dir * 16 + s) * 32], (unsigned int)(tau + 1));

            // Output stores off the critical path (drain overlaps next spin).
#pragma unroll
            for (int r = 0; r < 4; r++) {
                const int b = w * 16 + quad * 4 + r;
                __builtin_nontemporal_store(hv[r], &out[((size_t)b * T_SEQ + t) * 512 + dir * 256 + s * 16 + l16]);
            }
        }
    } else {
        // ================= XPROJ body (stage-remapped, sc1 stores, counter signal) =================
        const int xp4 = blockIdx.x - 32;          // [0, 8192)
        const int st  = xp4 >> 10;                // stage 0..7
        const int r1  = xp4 & 1023;
        const int dir = r1 >> 9;
        const int r2  = r1 & 511;
        const int yb  = r2 >> 6;                  // n-tile 0..7
        const int bb  = r2 & 63;                  // batch 0..63
        const int chunk = dir ? (7 - st) : st;    // t-chunk this block produces
        const int m0 = bb * 1024 + chunk * 128;   // 128 contiguous m within batch bb
        const int n0 = yb * 128;

        const float* W  = dir ? WihB : WihF;
        const float* bi = dir ? bihB : bihF;
        const float* bh = dir ? bhhB : bhhF;
        __hip_bfloat16* Xp = dir ? XpB : XpF;

        short* As = (short*)smem;                 // 128 x 32
        short* Bs = (short*)(smem + 8192);        // 128 x 32

        const int w2   = tid >> 6;
        const int wr   = w2 >> 1, wc = w2 & 1;    // 2x2 wave grid, 64x64 per wave
        const int srow = tid >> 2;                // staging row within 64-row half
        const int scg  = tid & 3;                 // 8-col group

        f32x4 acc[4][4] = {};

        for (int kk = 0; kk < 512; kk += 32) {
            const float* pa0 = X + (size_t)(m0 + srow)      * 512 + kk + scg * 8;
            const float* pa1 = X + (size_t)(m0 + 64 + srow) * 512 + kk + scg * 8;
            const float* pb0 = W + (size_t)(n0 + srow)      * 512 + kk + scg * 8;
            const float* pb1 = W + (size_t)(n0 + 64 + srow) * 512 + kk + scg * 8;
            bf8 a0 = pack_bf8(*(const float4*)pa0, *(const float4*)(pa0 + 4));
            bf8 a1 = pack_bf8(*(const float4*)pa1, *(const float4*)(pa1 + 4));
            bf8 b0 = pack_bf8(*(const float4*)pb0, *(const float4*)(pb0 + 4));
            bf8 b1 = pack_bf8(*(const float4*)pb1, *(const float4*)(pb1 + 4));
            __syncthreads();  // previous iteration's LDS reads done
            *(bf8*)&As[(srow)      * 32 + scg * 8] = a0;
            *(bf8*)&As[(64 + srow) * 32 + scg * 8] = a1;
            *(bf8*)&Bs[(srow)      * 32 + scg * 8] = b0;
            *(bf8*)&Bs[(64 + srow) * 32 + scg * 8] = b1;
            __syncthreads();

            bf8 af[4], bfr[4];
#pragma unroll
            for (int mt = 0; mt < 4; mt++)
                af[mt] = *(const bf8*)&As[(wr * 64 + mt * 16 + l16) * 32 + quad * 8];
#pragma unroll
            for (int nt = 0; nt < 4; nt++)
                bfr[nt] = *(const bf8*)&Bs[(wc * 64 + nt * 16 + l16) * 32 + quad * 8];
#pragma unroll
            for (int mt = 0; mt < 4; mt++)
#pragma unroll
                for (int nt = 0; nt < 4; nt++)
                    acc[mt][nt] = __builtin_amdgcn_mfma_f32_16x16x32_bf16(af[mt], bfr[nt], acc[mt][nt], 0, 0, 0);
        }

        // Epilogue: sc1 write-through stores (visible at LLC), then drain + signal.
#pragma unroll
        for (int nt = 0; nt < 4; nt++) {
            const int n = n0 + wc * 64 + nt * 16 + l16;
            const float bias = bi[n] + bh[n];
#pragma unroll
            for (int mt = 0; mt < 4; mt++) {
#pragma unroll
                for (int r = 0; r < 4; r++) {
                    const int m = m0 + wr * 64 + mt * 16 + quad * 4 + r;   // C/D: row=quad*4+r, col=l16
                    const int b = m >> 10, t = m & 1023;                    // m = b*1024 + t
                    store_sc1_b16(&Xp[((size_t)t * 64 + b) * 1024 + n],
                                  (unsigned short)bf16s(acc[mt][nt][r] + bias));
                }
            }
        }
        asm volatile("s_waitcnt vmcnt(0)" ::: "memory");   // per-wave drain: Xp in LLC
        __syncthreads();                                    // all waves drained
        if (tid == 0) atomicAdd(&cnt[dir * 8 + chunk], 1);  // device-scope, lands at LLC
    }
}

extern "C" void kernel_launch(void* const* d_in, const int* in_sizes, int n_in,
                              void* d_out, int out_size, void* d_ws, size_t ws_size,
                              hipStream_t stream)
{
    const float* X    = (const float*)d_in[0];
    const float* WihF = (const float*)d_in[1];
    const float* WhhF = (const float*)d_in[2];
    const float* bihF = (const float*)d_in[3];
    const float* bhhF = (const float*)d_in[4];
    const float* WihB = (const float*)d_in[5];
    const float* WhhB = (const float*)d_in[6];
    const float* bihB = (const float*)d_in[7];
    const float* bhhB = (const float*)d_in[8];
    float* out = (float*)d_out;

    char* ws = (char*)d_ws;
    __hip_bfloat16* XpF   = (__hip_bfloat16*)ws;                           // 128 MB
    __hip_bfloat16* XpB   = (__hip_bfloat16*)(ws + 134217728);             // 128 MB
    __hip_bfloat16* hexch = (__hip_bfloat16*)(ws + 268435456);             // 128 KB
    int*            flags = (int*)(ws + 268435456 + 131072);               // 4 KB (128 B spacing)
    int*            cnt   = (int*)(ws + 268435456 + 131072 + 4096);        // 64 B

    // Zero h_0 buffers, flags (0 == "h_0 ready") and chunk counters each replay.
    const int initN = (131072 + 4096 + 64) / 4;
    init_kernel<<<(initN + 255) / 256, 256, 0, stream>>>((unsigned int*)(ws + 268435456), initN);

    // One fused dispatch: 32 rec WGs (dispatched first) + 8192 stage-ordered xproj WGs.
    fused_kernel<<<8224, 256, 0, stream>>>(X, WihF, bihF, bhhF, WihB, bihB, bhhB,
                                           WhhF, WhhB, XpF, XpB, hexch, flags, cnt, out);
}